// Round 1
// baseline (90.504 us; speedup 1.0000x reference)
//
#include <hip/hip_runtime.h>
#include <math.h>

#define M 64
#define NSEG 16

__global__ __launch_bounds__(256)
void counter_kernel(const float* __restrict__ boxes,
                    const float* __restrict__ attn,
                    const float* __restrict__ fw,
                    float* __restrict__ out)
{
    // Packed piecewise-linear tables: cw_s[k][i] = {csum[i], w[min(i+1,16)]}
    __shared__ float2 cw_s[8][NSEG + 1];
    __shared__ float att_s[M];
    __shared__ float x1_s[M], y1_s[M], x2_s[M], y2_s[M], area_s[M];
    __shared__ float A_s[M * M];    // A[j][k]  = f0(rel)*f1(dist)
    __shared__ float ds_s[M * M];   // ds[j][k] = f3(rel)*f4(dist)
    __shared__ float partial_s[256];
    __shared__ float invrs_s[M];
    __shared__ float redA_s[4], redB_s[4], redC_s[4];
    __shared__ float bcast_s[3];

    const int n = blockIdx.x;
    const int t = threadIdx.x;

    // ---- Stage tables + per-sample inputs ----
    if (t < 8) {
        float wv[NSEG + 1];
        float s = 0.f;
        #pragma unroll
        for (int i = 0; i <= NSEG; ++i) { wv[i] = fabsf(fw[t * (NSEG + 1) + i]); s += wv[i]; }
        const float inv = 1.0f / s;
        #pragma unroll
        for (int i = 0; i <= NSEG; ++i) wv[i] *= inv;
        float c = 0.f;
        #pragma unroll
        for (int i = 0; i <= NSEG; ++i) {
            c += wv[i];
            cw_s[t][i] = make_float2(c, wv[i < NSEG ? i + 1 : NSEG]);
        }
    }
    if (t < M) {
        att_s[t] = attn[n * M + t];
        const float xa = boxes[n * 4 * M + 0 * M + t];
        const float ya = boxes[n * 4 * M + 1 * M + t];
        const float xb = boxes[n * 4 * M + 2 * M + t];
        const float yb = boxes[n * 4 * M + 3 * M + t];
        x1_s[t] = xa; y1_s[t] = ya; x2_s[t] = xb; y2_s[t] = yb;
        area_s[t] = fmaxf(xb - xa, 0.f) * fmaxf(yb - ya, 0.f);
    }
    __syncthreads();

    // plin matching the reference exactly: y=16x; idx=clip(trunc(y),0,16);
    // f=y-floor(y); csum[idx] + f*w[min(idx+1,16)]
    auto plin = [&](int k, float x) -> float {
        const float y = 16.0f * x;
        int idx = (int)y;
        idx = idx < 0 ? 0 : (idx > NSEG ? NSEG : idx);
        const float fr = y - floorf(y);
        const float2 cw = cw_s[k][idx];
        return cw.x + fr * cw.y;
    };

    // ---- Pass 1: per-pair dist, A, dedup_score, dist-conf partial ----
    float dc_local = 0.f;
    for (int p = t; p < M * M; p += 256) {
        const int j = p >> 6, k = p & (M - 1);
        const float rel = att_s[j] * att_s[k];
        const float mx = fmaxf(x1_s[j], x1_s[k]);
        const float my = fmaxf(y1_s[j], y1_s[k]);
        const float Mx = fminf(x2_s[j], x2_s[k]);
        const float My = fminf(y2_s[j], y2_s[k]);
        const float inter = fmaxf(Mx - mx, 0.f) * fmaxf(My - my, 0.f);
        const float iou = inter / (area_s[j] + area_s[k] - inter + 1e-12f);
        const float dist = 1.0f - iou;
        A_s[p]  = plin(0, rel) * plin(1, dist);
        ds_s[p] = plin(3, rel) * plin(4, dist);
        dc_local += fabsf(plin(6, dist) - 0.5f);
    }
    const float ac_local = (t < M) ? fabsf(plin(5, att_s[t]) - 0.5f) : 0.f;

    // reduce dist-conf / att-conf partials (wave=64 shuffles)
    {
        float vA = dc_local, vB = ac_local;
        #pragma unroll
        for (int off = 32; off > 0; off >>= 1) {
            vA += __shfl_down(vA, off, 64);
            vB += __shfl_down(vB, off, 64);
        }
        if ((t & 63) == 0) { redA_s[t >> 6] = vA; redB_s[t >> 6] = vB; }
    }
    __syncthreads();   // ds_s / A_s now visible to all

    // ---- Pass 2: sim products; thread t owns j=t>>2, 16 contiguous k ----
    const int j = t >> 2;
    const int k0 = (t & 3) << 4;
    float prod[16];
    #pragma unroll
    for (int q = 0; q < 16; ++q) prod[q] = 1.f;
    for (int i = 0; i < M; ++i) {
        const float aij = ds_s[i * M + j];
        #pragma unroll
        for (int q = 0; q < 16; ++q) {
            const float d = fabsf(aij - ds_s[i * M + k0 + q]);
            prod[q] *= plin(2, 1.0f - d);
        }
    }
    {
        const float aj = att_s[j];
        float psum = 0.f;
        #pragma unroll
        for (int q = 0; q < 16; ++q) {
            const float d = fabsf(aj - att_s[k0 + q]);
            psum += prod[q] * plin(2, 1.0f - d);
        }
        partial_s[t] = psum;
    }
    __syncthreads();
    if (t < M) {
        const float rs = partial_s[4 * t] + partial_s[4 * t + 1] +
                         partial_s[4 * t + 2] + partial_s[4 * t + 3];
        invrs_s[t] = 1.0f / rs;
    }
    __syncthreads();

    // ---- Pass 3: score = sum A/(rs_j*rs_k) + sum att_sq/rs ----
    float sc_local = 0.f;
    for (int p = t; p < M * M; p += 256) {
        const int jj = p >> 6, kk = p & (M - 1);
        sc_local += A_s[p] * (invrs_s[jj] * invrs_s[kk]);
    }
    if (t < M) sc_local += plin(0, att_s[t] * att_s[t]) * invrs_s[t];
    {
        float vC = sc_local;
        #pragma unroll
        for (int off = 32; off > 0; off >>= 1) vC += __shfl_down(vC, off, 64);
        if ((t & 63) == 0) redC_s[t >> 6] = vC;
    }
    __syncthreads();

    if (t == 0) {
        const float score_sum = redC_s[0] + redC_s[1] + redC_s[2] + redC_s[3];
        const float score = sqrtf(score_sum + 1e-20f);
        const float dc_mean = (redA_s[0] + redA_s[1] + redA_s[2] + redA_s[3]) * (1.0f / (M * M));
        const float ac_mean = (redB_s[0] + redB_s[1] + redB_s[2] + redB_s[3]) * (1.0f / M);
        const float conf = plin(7, ac_mean + dc_mean);
        const float scc = fminf(fmaxf(score, 0.f), 10.0f);
        const float fl = floorf(scc);
        bcast_s[0] = conf;
        bcast_s[1] = fl;
        bcast_s[2] = scc - fl;
    }
    __syncthreads();

    if (t < 11) {
        const float conf = bcast_s[0];
        const int i0 = (int)bcast_s[1];
        const float frac = bcast_s[2];
        const int i1 = i0 > 10 ? 10 : i0;
        const int i2 = (i0 + 1) > 10 ? 10 : (i0 + 1);
        float v = 0.f;
        if (t == i1) v += 1.0f - frac;
        if (t == i2) v += frac;
        out[n * 11 + t] = v * conf;
    }
}

extern "C" void kernel_launch(void* const* d_in, const int* in_sizes, int n_in,
                              void* d_out, int out_size, void* d_ws, size_t ws_size,
                              hipStream_t stream) {
    const float* boxes = (const float*)d_in[0];   // (n,4,64) f32
    const float* attn  = (const float*)d_in[1];   // (n,64)   f32
    const float* fw    = (const float*)d_in[2];   // (16,17)  f32
    float* out = (float*)d_out;                   // (n,11)   f32
    const int n = in_sizes[1] / M;
    counter_kernel<<<dim3(n), dim3(256), 0, stream>>>(boxes, attn, fw, out);
}

// Round 2
// 78.414 us; speedup vs baseline: 1.1542x; 1.1542x over previous
//
#include <hip/hip_runtime.h>
#include <math.h>

#define M 64
#define NSEG 16
#define THREADS 1024

__global__ __launch_bounds__(THREADS, 4)
void counter_kernel(const float* __restrict__ boxes,
                    const float* __restrict__ attn,
                    const float* __restrict__ fw,
                    float* __restrict__ out)
{
    // Packed piecewise-linear tables: cw_s[k][i] = {csum[i], w[min(i+1,16)]}
    __shared__ float2 cw_s[8][NSEG + 1];
    __shared__ float att_s[M];
    __shared__ float x1_s[M], y1_s[M], x2_s[M], y2_s[M], area_s[M];
    __shared__ float A_s[M * M];    // A[j][k]  = f0(rel)*f1(dist)
    __shared__ float ds_s[M * M];   // ds[j][k] = f3(rel)*f4(dist)
    __shared__ float invrs_s[M];
    __shared__ float redA_s[16], redB_s[16], redC_s[16];
    __shared__ float bcast_s[3];

    const int n = blockIdx.x;
    const int t = threadIdx.x;

    // ---- Stage tables + per-sample inputs ----
    if (t < 8) {
        float wv[NSEG + 1];
        float s = 0.f;
        #pragma unroll
        for (int i = 0; i <= NSEG; ++i) { wv[i] = fabsf(fw[t * (NSEG + 1) + i]); s += wv[i]; }
        const float inv = 1.0f / s;
        #pragma unroll
        for (int i = 0; i <= NSEG; ++i) wv[i] *= inv;
        float c = 0.f;
        #pragma unroll
        for (int i = 0; i <= NSEG; ++i) {
            c += wv[i];
            cw_s[t][i] = make_float2(c, wv[i < NSEG ? i + 1 : NSEG]);
        }
    }
    if (t < M) {
        att_s[t] = attn[n * M + t];
        const float xa = boxes[n * 4 * M + 0 * M + t];
        const float ya = boxes[n * 4 * M + 1 * M + t];
        const float xb = boxes[n * 4 * M + 2 * M + t];
        const float yb = boxes[n * 4 * M + 3 * M + t];
        x1_s[t] = xa; y1_s[t] = ya; x2_s[t] = xb; y2_s[t] = yb;
        area_s[t] = fmaxf(xb - xa, 0.f) * fmaxf(yb - ya, 0.f);
    }
    __syncthreads();

    // plin matching the reference exactly: y=16x; idx=clip(trunc(y),0,16);
    // f=y-floor(y); csum[idx] + f*w[min(idx+1,16)]
    auto plin = [&](int k, float x) -> float {
        const float y = 16.0f * x;
        int idx = (int)y;
        idx = idx < 0 ? 0 : (idx > NSEG ? NSEG : idx);
        const float fr = y - floorf(y);
        const float2 cw = cw_s[k][idx];
        return cw.x + fr * cw.y;
    };

    // ---- Pass 1: per-pair dist, A, dedup_score, dist-conf partial ----
    float dc_local = 0.f;
    for (int p = t; p < M * M; p += THREADS) {
        const int j = p >> 6, k = p & (M - 1);
        const float rel = att_s[j] * att_s[k];
        const float mx = fmaxf(x1_s[j], x1_s[k]);
        const float my = fmaxf(y1_s[j], y1_s[k]);
        const float Mx = fminf(x2_s[j], x2_s[k]);
        const float My = fminf(y2_s[j], y2_s[k]);
        const float inter = fmaxf(Mx - mx, 0.f) * fmaxf(My - my, 0.f);
        const float iou = inter / (area_s[j] + area_s[k] - inter + 1e-12f);
        const float dist = 1.0f - iou;
        A_s[p]  = plin(0, rel) * plin(1, dist);
        ds_s[p] = plin(3, rel) * plin(4, dist);
        dc_local += fabsf(plin(6, dist) - 0.5f);
    }
    const float ac_local = (t < M) ? fabsf(plin(5, att_s[t]) - 0.5f) : 0.f;

    // reduce dist-conf / att-conf partials (wave=64 shuffles)
    {
        float vA = dc_local, vB = ac_local;
        #pragma unroll
        for (int off = 32; off > 0; off >>= 1) {
            vA += __shfl_down(vA, off, 64);
            vB += __shfl_down(vB, off, 64);
        }
        if ((t & 63) == 0) { redA_s[t >> 6] = vA; redB_s[t >> 6] = vB; }
    }
    __syncthreads();   // ds_s / A_s now visible to all

    // ---- Pass 2: sim products; thread t owns j=t>>4, 4 contiguous k ----
    const int j = t >> 4;          // 0..63, 16 consecutive lanes share j
    const int k0 = (t & 15) << 2;  // 0,4,...,60
    float prod[4];
    #pragma unroll
    for (int q = 0; q < 4; ++q) prod[q] = 1.f;
    for (int i = 0; i < M; ++i) {
        const float aij = ds_s[i * M + j];                       // broadcast in 16-lane group
        const float4 kv = *(const float4*)&ds_s[i * M + k0];     // one ds_read_b128
        const float d0 = fabsf(aij - kv.x);
        const float d1 = fabsf(aij - kv.y);
        const float d2 = fabsf(aij - kv.z);
        const float d3 = fabsf(aij - kv.w);
        prod[0] *= plin(2, 1.0f - d0);
        prod[1] *= plin(2, 1.0f - d1);
        prod[2] *= plin(2, 1.0f - d2);
        prod[3] *= plin(2, 1.0f - d3);
    }
    {
        const float aj = att_s[j];
        const float4 av = *(const float4*)&att_s[k0];
        float psum = prod[0] * plin(2, 1.0f - fabsf(aj - av.x))
                   + prod[1] * plin(2, 1.0f - fabsf(aj - av.y))
                   + prod[2] * plin(2, 1.0f - fabsf(aj - av.z))
                   + prod[3] * plin(2, 1.0f - fabsf(aj - av.w));
        // reduce across the 16 lanes sharing j (consecutive lanes)
        #pragma unroll
        for (int off = 8; off > 0; off >>= 1) psum += __shfl_down(psum, off, 64);
        if ((t & 15) == 0) invrs_s[j] = 1.0f / psum;
    }
    __syncthreads();

    // ---- Pass 3: score = sum A/(rs_j*rs_k) + sum att_sq/rs ----
    float sc_local = 0.f;
    for (int p = t; p < M * M; p += THREADS) {
        const int jj = p >> 6, kk = p & (M - 1);
        sc_local += A_s[p] * (invrs_s[jj] * invrs_s[kk]);
    }
    if (t < M) sc_local += plin(0, att_s[t] * att_s[t]) * invrs_s[t];
    {
        float vC = sc_local;
        #pragma unroll
        for (int off = 32; off > 0; off >>= 1) vC += __shfl_down(vC, off, 64);
        if ((t & 63) == 0) redC_s[t >> 6] = vC;
    }
    __syncthreads();

    if (t == 0) {
        float score_sum = 0.f, dcs = 0.f, acs = 0.f;
        #pragma unroll
        for (int w = 0; w < 16; ++w) { score_sum += redC_s[w]; dcs += redA_s[w]; acs += redB_s[w]; }
        const float score = sqrtf(score_sum + 1e-20f);
        const float dc_mean = dcs * (1.0f / (M * M));
        const float ac_mean = acs * (1.0f / M);
        const float conf = plin(7, ac_mean + dc_mean);
        const float scc = fminf(fmaxf(score, 0.f), 10.0f);
        const float fl = floorf(scc);
        bcast_s[0] = conf;
        bcast_s[1] = fl;
        bcast_s[2] = scc - fl;
    }
    __syncthreads();

    if (t < 11) {
        const float conf = bcast_s[0];
        const int i0 = (int)bcast_s[1];
        const float frac = bcast_s[2];
        const int i1 = i0 > 10 ? 10 : i0;
        const int i2 = (i0 + 1) > 10 ? 10 : (i0 + 1);
        float v = 0.f;
        if (t == i1) v += 1.0f - frac;
        if (t == i2) v += frac;
        out[n * 11 + t] = v * conf;
    }
}

extern "C" void kernel_launch(void* const* d_in, const int* in_sizes, int n_in,
                              void* d_out, int out_size, void* d_ws, size_t ws_size,
                              hipStream_t stream) {
    const float* boxes = (const float*)d_in[0];   // (n,4,64) f32
    const float* attn  = (const float*)d_in[1];   // (n,64)   f32
    const float* fw    = (const float*)d_in[2];   // (16,17)  f32
    float* out = (float*)d_out;                   // (n,11)   f32
    const int n = in_sizes[1] / M;
    counter_kernel<<<dim3(n), dim3(THREADS), 0, stream>>>(boxes, attn, fw, out);
}

// Round 4
// 74.953 us; speedup vs baseline: 1.2075x; 1.0462x over previous
//
#include <hip/hip_runtime.h>
#include <math.h>

#define M 64
#define NSEG 16
#define NS 2                 // i-split: 2 blocks per sample, 32-deep each

#define STAGE_TABLES()                                                            \
    if (t < 8) {                                                                  \
        float wv[NSEG + 1];                                                       \
        float ssum = 0.f;                                                         \
        _Pragma("unroll")                                                         \
        for (int i = 0; i <= NSEG; ++i) { wv[i] = fabsf(fw[t*(NSEG+1)+i]); ssum += wv[i]; } \
        const float inv = 1.0f / ssum;                                            \
        _Pragma("unroll")                                                         \
        for (int i = 0; i <= NSEG; ++i) wv[i] *= inv;                             \
        float csum = 0.f;                                                         \
        _Pragma("unroll")                                                         \
        for (int i = 0; i <= NSEG; ++i) {                                         \
            csum += wv[i];                                                        \
            cw_s[t][i] = make_float2(csum, wv[i < NSEG ? i + 1 : NSEG]);          \
        }                                                                         \
    }

#define STAGE_INPUTS()                                                            \
    if (t < M) {                                                                  \
        att_s[t] = attn[n * M + t];                                               \
        const float xa = boxes[n*4*M + 0*M + t];                                  \
        const float ya = boxes[n*4*M + 1*M + t];                                  \
        const float xb = boxes[n*4*M + 2*M + t];                                  \
        const float yb = boxes[n*4*M + 3*M + t];                                  \
        x1_s[t] = xa; y1_s[t] = ya; x2_s[t] = xb; y2_s[t] = yb;                   \
        area_s[t] = fmaxf(xb - xa, 0.f) * fmaxf(yb - ya, 0.f);                    \
    }

#define DEF_PLIN()                                                                \
    auto plin = [&](int kk, float x) -> float {                                   \
        const float y = 16.0f * x;                                                \
        int idx = (int)y;                                                         \
        idx = idx < 0 ? 0 : (idx > NSEG ? NSEG : idx);                            \
        const float fr = y - floorf(y);                                           \
        const float2 cw = cw_s[kk][idx];                                          \
        return cw.x + fr * cw.y;                                                  \
    };

#define PAIR_GEOM(j_, k_)                                                         \
    const float rel  = att_s[j_] * att_s[k_];                                     \
    const float mx = fmaxf(x1_s[j_], x1_s[k_]);                                   \
    const float my = fmaxf(y1_s[j_], y1_s[k_]);                                   \
    const float Mx = fminf(x2_s[j_], x2_s[k_]);                                   \
    const float My = fminf(y2_s[j_], y2_s[k_]);                                   \
    const float inter = fmaxf(Mx - mx, 0.f) * fmaxf(My - my, 0.f);                \
    const float iou  = inter / (area_s[j_] + area_s[k_] - inter + 1e-12f);        \
    const float dist = 1.0f - iou;

// ---------------- Kernel 1: partial dedup products over a 32-deep i-chunk ----------------
__global__ __launch_bounds__(1024, 4)
void k1_partial(const float* __restrict__ boxes,
                const float* __restrict__ attn,
                const float* __restrict__ fw,
                float4* __restrict__ ws4)
{
    __shared__ float2 cw_s[8][NSEG + 1];
    __shared__ float att_s[M];
    __shared__ float x1_s[M], y1_s[M], x2_s[M], y2_s[M], area_s[M];
    __shared__ float ds_s[M * M];

    const int n = blockIdx.x;
    const int s = blockIdx.y;
    const int t = threadIdx.x;

    STAGE_TABLES();
    STAGE_INPUTS();
    __syncthreads();
    DEF_PLIN();

    // dedup_score matrix (full)
    for (int p = t; p < M * M; p += 1024) {
        const int j = p >> 6, k = p & (M - 1);
        PAIR_GEOM(j, k);
        ds_s[p] = plin(3, rel) * plin(4, dist);
    }
    __syncthreads();

    // one chunk per thread: j = t>>4, k0 = (t&15)*4; product over i in [32s, 32s+32)
    const int j = t >> 4;
    const int k0 = (t & 15) << 2;
    const int ibase = s * 32;
    float p0 = 1.f, p1 = 1.f, p2 = 1.f, p3 = 1.f;
    #pragma unroll
    for (int ii = 0; ii < 32; ++ii) {
        const int i = ibase + ii;
        const float aij = ds_s[i * M + j];
        const float4 kv = *(const float4*)&ds_s[i * M + k0];
        p0 *= plin(2, 1.0f - fabsf(aij - kv.x));
        p1 *= plin(2, 1.0f - fabsf(aij - kv.y));
        p2 *= plin(2, 1.0f - fabsf(aij - kv.z));
        p3 *= plin(2, 1.0f - fabsf(aij - kv.w));
    }
    ws4[(n * NS + s) * 1024 + t] = make_float4(p0, p1, p2, p3);
}

// ---------------- Kernel 2: combine partials, row sums, score, epilogue ----------------
__global__ __launch_bounds__(1024, 4)
void k2_finish(const float* __restrict__ boxes,
               const float* __restrict__ attn,
               const float* __restrict__ fw,
               const float4* __restrict__ ws4,
               float* __restrict__ out)
{
    __shared__ float2 cw_s[8][NSEG + 1];
    __shared__ float att_s[M];
    __shared__ float x1_s[M], y1_s[M], x2_s[M], y2_s[M], area_s[M];
    __shared__ float A_s[M * M];
    __shared__ float sim_s[M * M];
    __shared__ float invrs_s[M];
    __shared__ float redA_s[16], redB_s[16], redC_s[16];
    __shared__ float bcast_s[3];

    const int n = blockIdx.x;
    const int t = threadIdx.x;

    STAGE_TABLES();
    STAGE_INPUTS();
    __syncthreads();
    DEF_PLIN();

    // A matrix + dist-conf partial (identical to R2-passed code)
    float dc_local = 0.f;
    for (int p = t; p < M * M; p += 1024) {
        const int j = p >> 6, k = p & (M - 1);
        PAIR_GEOM(j, k);
        A_s[p] = plin(0, rel) * plin(1, dist);
        dc_local += fabsf(plin(6, dist) - 0.5f);
    }
    const float ac_local = (t < M) ? fabsf(plin(5, att_s[t]) - 0.5f) : 0.f;
    {
        float vA = dc_local, vB = ac_local;
        #pragma unroll
        for (int off = 32; off > 0; off >>= 1) {
            vA += __shfl_down(vA, off, 64);
            vB += __shfl_down(vB, off, 64);
        }
        if ((t & 63) == 0) { redA_s[t >> 6] = vA; redB_s[t >> 6] = vB; }
    }

    // combine the NS partial products, apply att-diff factor
    {
        const int j = t >> 4;
        const int k0 = (t & 15) << 2;
        const float4 v0 = ws4[(n * NS + 0) * 1024 + t];
        const float4 v1 = ws4[(n * NS + 1) * 1024 + t];
        const float aj = att_s[j];
        const float s0 = v0.x * v1.x * plin(2, 1.0f - fabsf(aj - att_s[k0 + 0]));
        const float s1 = v0.y * v1.y * plin(2, 1.0f - fabsf(aj - att_s[k0 + 1]));
        const float s2 = v0.z * v1.z * plin(2, 1.0f - fabsf(aj - att_s[k0 + 2]));
        const float s3 = v0.w * v1.w * plin(2, 1.0f - fabsf(aj - att_s[k0 + 3]));
        *(float4*)&sim_s[j * M + k0] = make_float4(s0, s1, s2, s3);
    }
    __syncthreads();

    // row sums -> invrs
    {
        const int j = t >> 4, c = t & 15;
        float psum = sim_s[j * M + c] + sim_s[j * M + c + 16] +
                     sim_s[j * M + c + 32] + sim_s[j * M + c + 48];
        #pragma unroll
        for (int off = 8; off > 0; off >>= 1) psum += __shfl_down(psum, off, 64);
        if (c == 0) invrs_s[j] = 1.0f / psum;
    }
    __syncthreads();

    // score = sum A * invrs_j * invrs_k + sum att_sq * invrs
    float sc_local = 0.f;
    for (int p = t; p < M * M; p += 1024) {
        const int jj = p >> 6, kk = p & (M - 1);
        sc_local += A_s[p] * (invrs_s[jj] * invrs_s[kk]);
    }
    if (t < M) sc_local += plin(0, att_s[t] * att_s[t]) * invrs_s[t];
    {
        float vC = sc_local;
        #pragma unroll
        for (int off = 32; off > 0; off >>= 1) vC += __shfl_down(vC, off, 64);
        if ((t & 63) == 0) redC_s[t >> 6] = vC;
    }
    __syncthreads();

    if (t == 0) {
        float score_sum = 0.f, dcs = 0.f, acs = 0.f;
        #pragma unroll
        for (int w = 0; w < 16; ++w) { score_sum += redC_s[w]; dcs += redA_s[w]; acs += redB_s[w]; }
        const float score = sqrtf(score_sum + 1e-20f);
        const float conf = plin(7, acs * (1.0f / M) + dcs * (1.0f / (M * M)));
        const float scc = fminf(fmaxf(score, 0.f), 10.0f);
        const float fl = floorf(scc);
        bcast_s[0] = conf; bcast_s[1] = fl; bcast_s[2] = scc - fl;
    }
    __syncthreads();

    if (t < 11) {
        const float conf = bcast_s[0];
        const int i0 = (int)bcast_s[1];
        const float frac = bcast_s[2];
        const int i1 = i0 > 10 ? 10 : i0;
        const int i2 = (i0 + 1) > 10 ? 10 : (i0 + 1);
        float v = 0.f;
        if (t == i1) v += 1.0f - frac;
        if (t == i2) v += frac;
        out[n * 11 + t] = v * conf;
    }
}

extern "C" void kernel_launch(void* const* d_in, const int* in_sizes, int n_in,
                              void* d_out, int out_size, void* d_ws, size_t ws_size,
                              hipStream_t stream) {
    const float* boxes = (const float*)d_in[0];   // (n,4,64) f32
    const float* attn  = (const float*)d_in[1];   // (n,64)   f32
    const float* fw    = (const float*)d_in[2];   // (16,17)  f32
    float* out = (float*)d_out;                   // (n,11)   f32
    const int n = in_sizes[1] / M;
    float4* ws4 = (float4*)d_ws;                  // n*NS*1024 float4 = 4 MB

    k1_partial<<<dim3(n, NS), dim3(1024), 0, stream>>>(boxes, attn, fw, ws4);
    k2_finish<<<dim3(n), dim3(1024), 0, stream>>>(boxes, attn, fw, ws4, out);
}